// Round 5
// baseline (7257.330 us; speedup 1.0000x reference)
//
#include <hip/hip_runtime.h>
#include <cstddef>

typedef __attribute__((ext_vector_type(8))) short short8;
typedef __attribute__((ext_vector_type(4))) short short4v;
typedef __attribute__((ext_vector_type(4))) float f32x4;

__device__ __forceinline__ unsigned short f2bf(float f){
  unsigned u = __builtin_bit_cast(unsigned, f);
  u += 0x7FFFu + ((u >> 16) & 1u);          // round-to-nearest-even
  return (unsigned short)(u >> 16);
}
__device__ __forceinline__ float bf2f(unsigned short h){
  unsigned u = ((unsigned)h) << 16;
  return __builtin_bit_cast(float, u);
}
__device__ __forceinline__ float sigf(float x){
  return __builtin_amdgcn_rcpf(1.0f + __builtin_amdgcn_exp2f(-1.4426950408889634f * x));
}
__device__ __forceinline__ float tanhf_(float x){
  return 1.0f - 2.0f * __builtin_amdgcn_rcpf(1.0f + __builtin_amdgcn_exp2f(2.8853900817779268f * x));
}

// inputs [32][1024][256] fp32 -> xbf [t*32+b][256] bf16
__global__ __launch_bounds__(64) void cast_x(const float* __restrict__ in, unsigned short* __restrict__ xb){
  int blk = blockIdx.x;              // b*1024 + t
  int t = blk & 1023, b = blk >> 10;
  int k = threadIdx.x * 4;
  float4 v = *(const float4*)(in + (size_t)blk * 256 + k);
  unsigned lo = f2bf(v.x) | ((unsigned)f2bf(v.y) << 16);
  unsigned hi = f2bf(v.z) | ((unsigned)f2bf(v.w) << 16);
  *(uint2*)(xb + ((size_t)t * 32 + b) * 256 + k) = make_uint2(lo, hi);
}

// Wih (fw,bw) fp32 -> Bw [2048][K] bf16 (row = dir*1024 + gatecol), bias[row] = bih+bhh
__global__ __launch_bounds__(64) void cast_w(const float* __restrict__ Wf, const float* __restrict__ Wb,
    const float* __restrict__ bihf, const float* __restrict__ bhhf,
    const float* __restrict__ bihb, const float* __restrict__ bhhb,
    unsigned short* __restrict__ Bw, float* __restrict__ bias, int K){
  int row = blockIdx.x;              // 0..2047
  int dd = row >> 10, gc = row & 1023;
  const float* src = (dd ? Wb : Wf) + (size_t)gc * K;
  unsigned short* dst = Bw + (size_t)row * K;
  for (int k = threadIdx.x * 4; k < K; k += 256){
    float4 v = *(const float4*)(src + k);
    unsigned lo = f2bf(v.x) | ((unsigned)f2bf(v.y) << 16);
    unsigned hi = f2bf(v.z) | ((unsigned)f2bf(v.w) << 16);
    *(uint2*)(dst + k) = make_uint2(lo, hi);
  }
  if (threadIdx.x == 0)
    bias[row] = dd ? (bihb[gc] + bhhb[gc]) : (bihf[gc] + bhhf[gc]);
}

// C[row=t*32+b][col 0..2047] = A[row][K] @ Bw[col][K]^T + bias[col], stored xg[t][col][b] bf16
__global__ __launch_bounds__(256) void gemm_xg(const unsigned short* __restrict__ A,
    const unsigned short* __restrict__ Bw, const float* __restrict__ bias,
    unsigned short* __restrict__ xg, int K){
  __shared__ __align__(16) unsigned short Al[128 * 64];
  __shared__ __align__(16) unsigned short Bl[128 * 64];
  const int tid = threadIdx.x;
  const int w = tid >> 6, l = tid & 63, q = l >> 4, cl = l & 15;
  const int bm = blockIdx.x >> 4, bn = blockIdx.x & 15;
  const int wm = w & 1, wn = w >> 1;
  f32x4 acc[4][4];
#pragma unroll
  for (int nt = 0; nt < 4; ++nt){
    float bv = bias[bn * 128 + wn * 64 + nt * 16 + cl];
#pragma unroll
    for (int mt = 0; mt < 4; ++mt) acc[mt][nt] = (f32x4){bv, bv, bv, bv};
  }
  const unsigned short* Ab = A + (size_t)(bm * 128) * K;
  const unsigned short* Bb = Bw + (size_t)(bn * 128) * K;
  for (int k0 = 0; k0 < K; k0 += 64){
#pragma unroll
    for (int i = 0; i < 4; ++i){
      int task = tid + i * 256;
      int row = task >> 3, ch = task & 7;
      int sw = ((ch ^ (row & 7)) * 8);
      *(uint4*)(&Al[row * 64 + sw]) = *(const uint4*)(Ab + (size_t)row * K + k0 + ch * 8);
      *(uint4*)(&Bl[row * 64 + sw]) = *(const uint4*)(Bb + (size_t)row * K + k0 + ch * 8);
    }
    __syncthreads();
#pragma unroll
    for (int kt2 = 0; kt2 < 2; ++kt2){
      short8 af[4], bfv[4];
#pragma unroll
      for (int mt = 0; mt < 4; ++mt){
        int row = wm * 64 + mt * 16 + cl;
        af[mt] = *(const short8*)(&Al[row * 64 + (((kt2 * 4 + q) ^ (row & 7)) * 8)]);
      }
#pragma unroll
      for (int nt = 0; nt < 4; ++nt){
        int n = wn * 64 + nt * 16 + cl;
        bfv[nt] = *(const short8*)(&Bl[n * 64 + (((kt2 * 4 + q) ^ (n & 7)) * 8)]);
      }
#pragma unroll
      for (int mt = 0; mt < 4; ++mt)
#pragma unroll
        for (int nt = 0; nt < 4; ++nt)
          acc[mt][nt] = __builtin_amdgcn_mfma_f32_16x16x32_bf16(af[mt], bfv[nt], acc[mt][nt], 0, 0, 0);
    }
    __syncthreads();
  }
#pragma unroll
  for (int mt = 0; mt < 4; ++mt){
    int row = bm * 128 + wm * 64 + mt * 16 + q * 4;
    int tt = row >> 5, bb = row & 31;
#pragma unroll
    for (int nt = 0; nt < 4; ++nt){
      int col = bn * 128 + wn * 64 + nt * 16 + cl;
      f32x4 v = acc[mt][nt];
      unsigned lo = f2bf(v[0]) | ((unsigned)f2bf(v[1]) << 16);
      unsigned hi = f2bf(v[2]) | ((unsigned)f2bf(v[3]) << 16);
      *(uint2*)(xg + ((size_t)tt * 2048 + col) * 32 + bb) = make_uint2(lo, hi);
    }
  }
}

// ---------------------------------------------------------------------------
// Recurrent core v4: pairwise halves + LDS relay + same-XCD fast path,
// single hx buffer (round-2 memory map), dual cache-path transport.
// Grid 16 x 512. pair = bid&7, ch = bid>>3; pairs 0..3 work, 4..7 exit.
// Partner blocks {p, p+8} co-locate on one XCD under round-robin bid%8.
// Transport (tag-in-data, u32 = h_bf16<<16 | tag16, tag = t+1, 2 slots):
//   producer: plain store (shared per-XCD L2) + sc1 store (LLC), SAME addr.
//   consumer: sc0 load (L2) + sc1 load (LLC) of same addr; vmcnt(1) waits the
//     fast one; safe one drained after the MFMA cluster (latency hidden) with
//     an explicit keep-alive so its dest VGPRs stay live (round-4 lesson:
//     dangling asm loads + register reuse = corruption).
// Raw s_barrier (lgkmcnt(0) asm + builtin + memory fence) instead of
// __syncthreads so the compiler's vmcnt(0)-before-barrier drain never
// serializes the safe load / xn prefetch into the step critical path.
// If blocks don't co-locate the fast path never validates and the sc1 path
// gives exactly the round-2 protocol. Correctness never depends on placement.
// ---------------------------------------------------------------------------
#define ISSUE2() \
  asm volatile("global_load_dwordx4 %0, %2, off sc0\n\t" \
               "global_load_dwordx4 %1, %2, off sc1" \
    : "=v"(pvF), "=v"(pvS) : "v"(pb) : "memory")
#define WAITF() \
  asm volatile("s_waitcnt vmcnt(1)" ::: "memory"); \
  __builtin_amdgcn_sched_barrier(0)
#define WAITS() \
  asm volatile("s_waitcnt vmcnt(0)" ::: "memory"); \
  __builtin_amdgcn_sched_barrier(0)
#define CHKV(P) ( \
  xx = (P.x ^ tagv) | (P.y ^ tagv) | (P.z ^ tagv) | (P.w ^ tagv), \
  __all((xx & 0xFFFFu) == 0u) )

__global__ __launch_bounds__(512, 1) void lstm_rec(const unsigned short* __restrict__ xg,
    const float* __restrict__ WhhF, const float* __restrict__ WhhB,
    const float* __restrict__ mask, unsigned* __restrict__ hx,
    unsigned short* __restrict__ houts, float* __restrict__ out,
    float* __restrict__ hnout, float* __restrict__ cnout, int layer){
  __shared__ __align__(16) unsigned short hloc[2][16][136];  // own-half h, 272B row stride
  __shared__ __align__(16) unsigned short hrem[2][16][136];  // relayed partner-half h
  __shared__ __align__(16) float maskL[16384];               // [t(1024)][row(16)]
  const int tid = threadIdx.x;
  const int w = tid >> 6, l = tid & 63, q = l >> 4, cl = l & 15;
  const int bid = blockIdx.x;
  const int pair = bid & 7, ch = bid >> 3;
  if (pair >= 4) return;
  const int d = pair >> 1, g = pair & 1;
  const float* __restrict__ Whh = d ? WhhB : WhhF;
  const int jj = ch * 128 + w * 16 + cl;     // hidden col owned by this lane (0..255)
  const int ph = ch ^ 1;
  const int ch4 = ch * 4, ph4 = ph * 4;

  // Whh B-fragments: [gate][p], p 0..3 = local k-tiles, 4..7 = remote k-tiles
  short8 bfrag[4][8];
#pragma unroll
  for (int gi = 0; gi < 4; ++gi){
    const float* wg = Whh + (size_t)(gi * 256 + jj) * 256 + q * 8;
#pragma unroll
    for (int p = 0; p < 8; ++p){
      int gk = (p < 4) ? (ch4 + p) : (ph4 + (p - 4));
      float4 x0 = *(const float4*)(wg + gk * 32);
      float4 x1 = *(const float4*)(wg + gk * 32 + 4);
      short8 f;
      f[0] = (short)f2bf(x0.x); f[1] = (short)f2bf(x0.y); f[2] = (short)f2bf(x0.z); f[3] = (short)f2bf(x0.w);
      f[4] = (short)f2bf(x1.x); f[5] = (short)f2bf(x1.y); f[6] = (short)f2bf(x1.z); f[7] = (short)f2bf(x1.w);
      bfrag[gi][p] = f;
    }
  }
  // mask -> LDS, [t][row16] so activation reads one f32x4 per lane
  for (int i = tid; i < 16384; i += 512){
    int tt = i >> 4, r = i & 15;
    maskL[i] = mask[(size_t)(g * 16 + r) * 1024 + tt];
  }
  __syncthreads();

  float cst[4] = {0.f, 0.f, 0.f, 0.f};
  // per layer: [u(4)][slot(2)][row(16)][col(256)] u32 (131072 B) - round-2 map
  unsigned* hxu = hx + (size_t)(d * 2 + g) * 8192;
  // poll geometry: wave w owns rows {2w, 2w+1}; lane covers 4 cols of partner half
  const int rr = 2 * w + (l >> 5);
  const int cc = l & 31;
  const unsigned* plA = hxu + rr * 256 + ph * 128 + cc * 4;  // slot 0 (polled when par==1)
  const unsigned* plB = plA + 4096;                          // slot 1 (polled when par==0)
  unsigned* stA = hxu + (q * 4) * 256 + jj;                  // producer base, slot 0 (par==0)
  unsigned* stB = stA + 4096;
  const int bq = g * 16 + q * 4;
  const size_t dj = (size_t)d * 256 + jj;
  unsigned short* hob = houts + (size_t)bq * 512 + dj;      // + r*512 + ot*16384
  float* outb = out + (size_t)bq * 524288 + dj;             // + r*524288 + ot*512

  const ptrdiff_t tstep = d ? -65536 : 65536;
  const unsigned short* xcur = xg + (size_t)(d ? 1023 : 0) * 65536
                               + ((size_t)d * 1024 + jj) * 32 + g * 16 + q * 4;
  short4v xp[4], xn[4];
#pragma unroll
  for (int gi = 0; gi < 4; ++gi) xp[gi] = *(const short4v*)(xcur + gi * 8192);

#pragma unroll 2
  for (int t = 0; t < 1024; ++t){
    const int par = t & 1;
    const int ot = d ? (1023 - t) : t;
    // acc init from xp FIRST: the compiler's wait for last step's xn loads
    // lands here, before the polls are issued (never drains them).
    f32x4 acc[4];
#pragma unroll
    for (int gi = 0; gi < 4; ++gi)
      acc[gi] = (f32x4){bf2f((unsigned short)xp[gi][0]), bf2f((unsigned short)xp[gi][1]),
                        bf2f((unsigned short)xp[gi][2]), bf2f((unsigned short)xp[gi][3])};
    __builtin_amdgcn_sched_barrier(0);
    if (t > 0){
      const unsigned* pb = par ? plA : plB;
      uint4 pvF, pvS;
      ISSUE2();                                 // sc0 (fast) + sc1 (safe), same addr
      WAITF();                                  // fast landed (in-order retire)
      const unsigned tagv = (unsigned)t;
      unsigned xx; uint4 pv;
      if (CHKV(pvF)) pv = pvF;
      else {
        for (;;){
          WAITS();                              // drain safe too
          if (CHKV(pvS)) { pv = pvS; break; }
          ISSUE2();
          WAITF();
          if (CHKV(pvF)) { pv = pvF; break; }
        }
      }
      // relay: strip tags, write this wave's 2 rows into hrem
      {
        unsigned lo = __builtin_amdgcn_perm(pv.y, pv.x, 0x07060302u);
        unsigned hi = __builtin_amdgcn_perm(pv.w, pv.z, 0x07060302u);
        *(uint2*)(&hrem[par][rr][cc * 4]) = make_uint2(lo, hi);
      }
      // raw barrier: LDS drained, vmcnt NOT drained (safe load stays in flight)
      asm volatile("s_waitcnt lgkmcnt(0)" ::: "memory");
      __builtin_amdgcn_s_barrier();
      asm volatile("" ::: "memory");
      __builtin_amdgcn_sched_barrier(0);
      // all 8 A-ktiles from LDS: local half (written last step) + relayed remote
      const unsigned short* lb = &hloc[par ^ 1][0][0];
      const unsigned short* rb = &hrem[par][0][0];
      const int ao = cl * 136 + q * 8;
#pragma unroll
      for (int ktl = 0; ktl < 4; ++ktl){
        short8 a = *(const short8*)(lb + ao + ktl * 32);
        acc[0] = __builtin_amdgcn_mfma_f32_16x16x32_bf16(a, bfrag[0][ktl], acc[0], 0, 0, 0);
        acc[1] = __builtin_amdgcn_mfma_f32_16x16x32_bf16(a, bfrag[1][ktl], acc[1], 0, 0, 0);
        acc[2] = __builtin_amdgcn_mfma_f32_16x16x32_bf16(a, bfrag[2][ktl], acc[2], 0, 0, 0);
        acc[3] = __builtin_amdgcn_mfma_f32_16x16x32_bf16(a, bfrag[3][ktl], acc[3], 0, 0, 0);
      }
#pragma unroll
      for (int ktl = 0; ktl < 4; ++ktl){
        short8 a = *(const short8*)(rb + ao + ktl * 32);
        acc[0] = __builtin_amdgcn_mfma_f32_16x16x32_bf16(a, bfrag[0][4 + ktl], acc[0], 0, 0, 0);
        acc[1] = __builtin_amdgcn_mfma_f32_16x16x32_bf16(a, bfrag[1][4 + ktl], acc[1], 0, 0, 0);
        acc[2] = __builtin_amdgcn_mfma_f32_16x16x32_bf16(a, bfrag[2][4 + ktl], acc[2], 0, 0, 0);
        acc[3] = __builtin_amdgcn_mfma_f32_16x16x32_bf16(a, bfrag[3][4 + ktl], acc[3], 0, 0, 0);
      }
      // drain the (possibly) dangling safe load; keep its registers alive to
      // here so the late write-back can never corrupt reused VGPRs.
      asm volatile("s_waitcnt vmcnt(0)" ::: "memory");
      asm volatile("" :: "v"(pvS.x), "v"(pvS.y), "v"(pvS.z), "v"(pvS.w));
      __builtin_amdgcn_sched_barrier(0);
    }
    // next-step xg prefetch: issued after the drain so it sits under
    // activation/stores/next acc-init, never under a barrier or poll wait.
    if (t < 1023){
#pragma unroll
      for (int gi = 0; gi < 4; ++gi) xn[gi] = *(const short4v*)(xcur + tstep + gi * 8192);
    }
    // activation: lane (q,cl) holds col jj, rows 4q..4q+3 of the 16-row tile
    f32x4 mv = *(const f32x4*)(&maskL[ot * 16 + q * 4]);
    float hv[4]; unsigned short hb[4];
#pragma unroll
    for (int r = 0; r < 4; ++r){
      float ig = sigf(acc[0][r]);
      float fg = sigf(acc[1][r]);
      float gg = tanhf_(acc[2][r]);
      float og = sigf(acc[3][r]);
      float cn = fg * cst[r] + ig * gg;
      float hn = og * tanhf_(cn);
      float m = mv[r];
      hn *= m; cn *= m;
      cst[r] = cn; hv[r] = hn; hb[r] = f2bf(hn);
    }
    // partner-visible stores first (latency-critical): plain (shared L2 when
    // co-located) + sc1 (LLC, always-correct), same address. Then LDS, outputs.
    {
      unsigned* sw = par ? stB : stA;
      const unsigned tagn = (unsigned)(t + 1);
      unsigned w0 = ((unsigned)hb[0] << 16) | tagn;
      unsigned w1 = ((unsigned)hb[1] << 16) | tagn;
      unsigned w2 = ((unsigned)hb[2] << 16) | tagn;
      unsigned w3 = ((unsigned)hb[3] << 16) | tagn;
      asm volatile(
        "global_store_dword %0, %1, off\n\t"
        "global_store_dword %0, %2, off offset:1024\n\t"
        "global_store_dword %0, %3, off offset:2048\n\t"
        "global_store_dword %0, %4, off offset:3072\n\t"
        "global_store_dword %0, %1, off sc1\n\t"
        "global_store_dword %0, %2, off offset:1024 sc1\n\t"
        "global_store_dword %0, %3, off offset:2048 sc1\n\t"
        "global_store_dword %0, %4, off offset:3072 sc1"
        :: "v"(sw), "v"(w0), "v"(w1), "v"(w2), "v"(w3)
        : "memory");
    }
#pragma unroll
    for (int r = 0; r < 4; ++r) hloc[par][q * 4 + r][w * 16 + cl] = hb[r];
    if (layer == 0){
#pragma unroll
      for (int r = 0; r < 4; ++r) hob[(size_t)ot * 16384 + r * 512] = hb[r];
    } else {
#pragma unroll
      for (int r = 0; r < 4; ++r) outb[(size_t)r * 524288 + (size_t)ot * 512] = hv[r];
    }
    if (t == 1023){
#pragma unroll
      for (int r = 0; r < 4; ++r){
        size_t bo = (size_t)(layer * 32 + bq + r) * 512 + dj;
        hnout[bo] = hv[r];
        cnout[bo] = cst[r];
      }
    }
    if (t < 1023){
#pragma unroll
      for (int gi = 0; gi < 4; ++gi) xp[gi] = xn[gi];
    }
    xcur += tstep;
  }
}

extern "C" void kernel_launch(void* const* d_in, const int* in_sizes, int n_in,
                              void* d_out, int out_size, void* d_ws, size_t ws_size,
                              hipStream_t stream){
  const float* inputs  = (const float*)d_in[0];
  const float* mask    = (const float*)d_in[1];
  const float* l0f_Wih = (const float*)d_in[2];
  const float* l0f_Whh = (const float*)d_in[3];
  const float* l0f_bih = (const float*)d_in[4];
  const float* l0f_bhh = (const float*)d_in[5];
  const float* l0b_Wih = (const float*)d_in[6];
  const float* l0b_Whh = (const float*)d_in[7];
  const float* l0b_bih = (const float*)d_in[8];
  const float* l0b_bhh = (const float*)d_in[9];
  const float* l1f_Wih = (const float*)d_in[10];
  const float* l1f_Whh = (const float*)d_in[11];
  const float* l1f_bih = (const float*)d_in[12];
  const float* l1f_bhh = (const float*)d_in[13];
  const float* l1b_Wih = (const float*)d_in[14];
  const float* l1b_Whh = (const float*)d_in[15];
  const float* l1b_bih = (const float*)d_in[16];
  const float* l1b_bhh = (const float*)d_in[17];

  char* ws = (char*)d_ws;
  unsigned short* xg   = (unsigned short*)(ws);                 // [1024][2048][32] bf16, 134217728 B
  unsigned short* xbf  = (unsigned short*)(ws + 134217728);     // [32768][256]  bf16, 16777216 B
  unsigned short* hout = (unsigned short*)(ws + 150994944);     // [32768][512]  bf16, 33554432 B
  unsigned short* B0   = (unsigned short*)(ws + 184549376);     // [2048][256]   bf16, 1048576 B
  unsigned short* B1   = (unsigned short*)(ws + 185597952);     // [2048][512]   bf16, 2097152 B
  float* bias0         = (float*)(ws + 187695104);              // [2048] f32
  float* bias1         = (float*)(ws + 187703296);              // [2048] f32
  unsigned* hx         = (unsigned*)(ws + 187711488);           // 2 layers x [4 units][2 slots][16][256] u32

  float* out   = (float*)d_out;          // [32][1024][512]
  float* hnout = out + 16777216;         // [2][32][512]
  float* cnout = hnout + 32768;          // [2][32][512]

  hipMemsetAsync(hx, 0, 262144, stream);  // tag16 = 0, never matches tags 1..1024
  cast_x<<<32768, 64, 0, stream>>>(inputs, xbf);
  cast_w<<<2048, 64, 0, stream>>>(l0f_Wih, l0b_Wih, l0f_bih, l0f_bhh, l0b_bih, l0b_bhh, B0, bias0, 256);
  cast_w<<<2048, 64, 0, stream>>>(l1f_Wih, l1b_Wih, l1f_bih, l1f_bhh, l1b_bih, l1b_bhh, B1, bias1, 512);
  gemm_xg<<<4096, 256, 0, stream>>>(xbf, B0, bias0, xg, 256);
  lstm_rec<<<16, 512, 0, stream>>>(xg, l0f_Whh, l0b_Whh, mask, hx, hout, nullptr, hnout, cnout, 0);
  gemm_xg<<<4096, 256, 0, stream>>>(hout, B1, bias1, xg, 512);
  lstm_rec<<<16, 512, 0, stream>>>(xg, l1f_Whh, l1b_Whh, mask, hx + 32768, nullptr, out, hnout, cnout, 1);
}